// Round 17
// baseline (1117.166 us; speedup 1.0000x reference)
//
#include <hip/hip_runtime.h>
#include <hip/hip_bf16.h>
#include <math.h>

#define NEXP 8
#define DDIM 1024
#define FFDIM 4096
#define NTOK 8192
#define NSLOT (NTOK * 2)
#define BM 128
#define BN2 256              /* block tile: 128 x 256, 4 waves of 128x64 */
#define BK 64
#define MAXT ((NSLOT / BM) + NEXP) /* 136 worst-case row tiles */

typedef __attribute__((ext_vector_type(8))) __bf16 bf16x8;
typedef __attribute__((ext_vector_type(4))) __bf16 bf16x4;
typedef __attribute__((ext_vector_type(4))) float f32x4;

union BF8 { __bf16 b[8]; uint4 u; bf16x8 v; };

// async global->LDS, 16B per lane; LDS dest = wave-uniform base + lane*16
typedef const __attribute__((address_space(1))) void* gptr1_t;
typedef __attribute__((address_space(3))) void* lptr3_t;
__device__ __forceinline__ void gll16(const void* g, void* l) {
    __builtin_amdgcn_global_load_lds((gptr1_t)g, (lptr3_t)l, 16, 0, 0);
}

// Fast GELU (tanh form) — ~1e-4 max abs dev from exact erf form.
__device__ __forceinline__ float gelu_fast(float v) {
    float vv = v * v;
    float ex = __expf(v * fmaf(0.0713548162726f, vv, 1.59576912161f));
    float s = __builtin_amdgcn_rcpf(ex + 1.0f);
    return v * (1.0f - s);
}

// Swizzled byte offset inside a [rows][64 bf16] tile (128B rows).
__device__ __forceinline__ int swz(int row, int colb) {
    return row * 128 + (colb ^ ((row & 7) << 4));
}

// XCD chunked swizzle (gemm2 only — measured win there, loss on gemm1).
__device__ __forceinline__ int xcd_logical(int bid, int nwg) {
    if (nwg & 7) return bid;
    return (bid & 7) * (nwg >> 3) + (bid >> 3);
}

// ---------------- router + fused x->bf16 conversion ----------------
__global__ __launch_bounds__(256)
void router_kernel(const float* __restrict__ x, const float* __restrict__ Wr,
                   __bf16* __restrict__ xb, int write_xb,
                   int* __restrict__ idx2, float* __restrict__ gates2,
                   int* __restrict__ counts)
{
    int tid = threadIdx.x;
    int t = blockIdx.x * 4 + (tid >> 6);
    int lane = tid & 63;
    const float* xr = x + (size_t)t * DDIM;

    float acc[NEXP];
#pragma unroll
    for (int e = 0; e < NEXP; ++e) acc[e] = 0.f;

#pragma unroll
    for (int i = 0; i < 2; ++i) {
        int d0 = i * 512 + lane * 8;
        float4 a = *(const float4*)(xr + d0);
        float4 b = *(const float4*)(xr + d0 + 4);
        float vals[8] = {a.x, a.y, a.z, a.w, b.x, b.y, b.z, b.w};
#pragma unroll
        for (int q = 0; q < 8; ++q) {
            const float* wrow = Wr + (size_t)(d0 + q) * NEXP;
#pragma unroll
            for (int e = 0; e < NEXP; ++e) acc[e] += vals[q] * wrow[e];
        }
        if (write_xb) {
            BF8 pk;
#pragma unroll
            for (int q = 0; q < 8; ++q) pk.b[q] = (__bf16)vals[q];
            *(uint4*)(xb + (size_t)t * DDIM + d0) = pk.u;
        }
    }
#pragma unroll
    for (int e = 0; e < NEXP; ++e) {
        float v = acc[e];
        for (int off = 32; off > 0; off >>= 1) v += __shfl_xor(v, off, 64);
        acc[e] = v;
    }
    if (lane == 0) {
        float mx = acc[0];
#pragma unroll
        for (int e = 1; e < NEXP; ++e) mx = fmaxf(mx, acc[e]);
        float p[NEXP]; float s = 0.f;
#pragma unroll
        for (int e = 0; e < NEXP; ++e) { p[e] = expf(acc[e] - mx); s += p[e]; }
        float inv = 1.f / s;
#pragma unroll
        for (int e = 0; e < NEXP; ++e) p[e] *= inv;
        int i1 = 0; float p1 = p[0];
#pragma unroll
        for (int e = 1; e < NEXP; ++e) if (p[e] > p1) { p1 = p[e]; i1 = e; }
        int i2 = -1; float p2 = -1.f;
#pragma unroll
        for (int e = 0; e < NEXP; ++e) {
            if (e == i1) continue;
            if (p[e] > p2) { p2 = p[e]; i2 = e; }
        }
        float u = expf(p2 - p1);
        float den = 1.f + u;
        idx2[2 * t] = i1; idx2[2 * t + 1] = i2;
        gates2[2 * t] = 1.f / den; gates2[2 * t + 1] = u / den;
        atomicAdd(&counts[i1], 1);
        atomicAdd(&counts[i2], 1);
    }
}

// ---------------- offsets + tile table (parallel) ----------------
__global__ __launch_bounds__(256)
void offsets_kernel(const int* __restrict__ counts, int* __restrict__ offsets,
                    int* __restrict__ cursors, int* __restrict__ tiletab)
{
    __shared__ int soff[NEXP], stile[NEXP + 1];
    int tid = threadIdx.x;
    if (tid == 0) {
        int off = 0, tt = 0;
        for (int e = 0; e < NEXP; ++e) {
            soff[e] = off; stile[e] = tt;
            int c = counts[e];
            off += c; tt += (c + BM - 1) / BM;
        }
        stile[NEXP] = tt;
    }
    __syncthreads();
    if (tid < NEXP) { offsets[tid] = soff[tid]; cursors[tid] = 0; }
    int total = stile[NEXP];
    for (int i = tid; i < MAXT; i += 256) {
        if (i < total) {
            int e = 0;
            while (stile[e + 1] <= i) ++e;
            tiletab[2 * i] = e; tiletab[2 * i + 1] = i - stile[e];
        } else {
            tiletab[2 * i] = -1; tiletab[2 * i + 1] = 0;
        }
    }
}

// ---------------- fill permutation (+ inverse token->slots) ----------------
__global__ __launch_bounds__(256)
void fill_kernel(const int* __restrict__ idx2, const float* __restrict__ gates2,
                 const int* __restrict__ offsets, int* __restrict__ cursors,
                 int* __restrict__ perm, float* __restrict__ gate_slot,
                 int* __restrict__ tslot)
{
    int t = blockIdx.x * 256 + threadIdx.x;
    if (t >= NTOK) return;
#pragma unroll
    for (int s = 0; s < 2; ++s) {
        int e = idx2[2 * t + s];
        int pos = atomicAdd(&cursors[e], 1);
        int slot = offsets[e] + pos;
        perm[slot] = t;
        gate_slot[slot] = gates2[2 * t + s];
        tslot[2 * t + s] = slot;
    }
}

// Fused W1+W2 conversion with coalesced writes (r16-proven).
__global__ __launch_bounds__(256)
void convert_w_kernel(const float* __restrict__ W1, const float* __restrict__ W2,
                      __bf16* __restrict__ W1T, __bf16* __restrict__ W2T)
{
    __shared__ float tile[64][133];
    int y = blockIdx.y;
    const float* W; __bf16* WT; int K, N, e;
    if (y < NEXP) { W = W1; WT = W1T; K = DDIM; N = FFDIM; e = y; }
    else          { W = W2; WT = W2T; K = FFDIM; N = DDIM; e = y - NEXP; }
    int ktiles = K >> 6;
    int nt = blockIdx.x / ktiles;
    int kt = blockIdx.x % ktiles;
    const float* We = W + (size_t)e * K * N + (size_t)(kt * 64) * N + nt * 128;
    int tid = threadIdx.x;

    int kr = tid >> 5;
    int n4 = (tid & 31) * 4;
#pragma unroll
    for (int i = 0; i < 8; ++i) {
        int k = kr + i * 8;
        float4 v = *(const float4*)(We + (size_t)k * N + n4);
        tile[k][n4] = v.x; tile[k][n4 + 1] = v.y;
        tile[k][n4 + 2] = v.z; tile[k][n4 + 3] = v.w;
    }
    __syncthreads();

    char* dstb = (char*)WT + ((((size_t)e * (N >> 7) + nt) * ktiles + kt) << 14);
#pragma unroll
    for (int it = 0; it < 4; ++it) {
        int off = it * 4096 + tid * 16;
        int r = off >> 7;
        int s = (off >> 4) & 7;
        int gi = s ^ (r & 7);
        BF8 pk;
#pragma unroll
        for (int q = 0; q < 8; ++q) pk.b[q] = (__bf16)tile[gi * 8 + q][r];
        *(uint4*)(dstb + off) = pk.u;
    }
}

// ---------------- shared tile-header logic ----------------
__device__ __forceinline__ bool tile_header(const int* counts, const int* offsets,
                                            const int* tiletab, int e_arg, int c_arg, int CH,
                                            int tile_idx,
                                            int& e, int& start, int& cnt, int& hbase, int& row0,
                                            int& rows_here)
{
    int rowtile;
    if (e_arg >= 0) {
        e = e_arg;
        int cbase = c_arg * CH;
        cnt = counts[e] - cbase;
        if (cnt <= 0) return false;
        if (cnt > CH) cnt = CH;
        start = offsets[e] + cbase;
        rowtile = tile_idx;
        hbase = start;
    } else {
        e = tiletab[2 * tile_idx];
        if (e < 0) return false;
        rowtile = tiletab[2 * tile_idx + 1];
        start = offsets[e];
        cnt = counts[e];
        hbase = 0;
    }
    row0 = rowtile * BM;
    if (row0 >= cnt) return false;
    rows_here = cnt - row0;
    if (rows_here > BM) rows_here = BM;
    return true;
}

// ---------------- FAST GEMM1: 128x256 block, 4 waves of 128x64 ----------------
// A (16KB) shared by all waves; B = two pre-swizzled 16KB sub-panels (32KB).
// Per-wave: acc[8][4], 64 MFMA per K-step. ~30% less LDS traffic per FLOP.
__global__ __launch_bounds__(256)
void gemm1_fast(const __bf16* __restrict__ xb, const __bf16* __restrict__ W1T,
                const float* __restrict__ b1,
                const int* __restrict__ perm, const int* __restrict__ counts,
                const int* __restrict__ offsets, const int* __restrict__ tiletab,
                __bf16* __restrict__ H, int e_arg, int c_arg, int CH)
{
    __shared__ __align__(16) char smem[48 * 1024];
    char* As = smem;            // [128][64bf16] swizzled, 16KB
    char* Bs = smem + 16384;    // 2 sub-tiles x [128][64bf16] swizzled, 32KB

    int e, start, cnt, hbase, row0, rows_here;
    if (!tile_header(counts, offsets, tiletab, e_arg, c_arg, CH, blockIdx.y,
                     e, start, cnt, hbase, row0, rows_here))
        return;

    const float* b1e = b1 + (size_t)e * FFDIM;
    int ntb = blockIdx.x;                 // 0..15
    int n0 = ntb * BN2;
    const int ktiles = DDIM >> 6;         // 16
    const char* bpanel = (const char*)W1T +
        ((((size_t)e * (FFDIM >> 7) + 2 * ntb) * ktiles) << 14);
    const size_t substride = (size_t)ktiles << 14;

    int tid = threadIdx.x;
    int lane = tid & 63;
    int wid = tid >> 6;                   // n-strip 0..3
    int lr = lane & 15, lhi = lane >> 4;

    int ar = tid >> 1, ach = tid & 1;
    int token = -1;
    if (ar < rows_here) token = perm[start + row0 + ar];
    const __bf16* arow = xb + (size_t)(token < 0 ? 0 : token) * DDIM + ach * 32;

    int bsub = wid >> 1;
    const char* bsrcw = bpanel + bsub * substride + (wid & 1) * 8192 + lane * 16;
    char* bldsw = Bs + wid * 8192;
    const char* bfrag = Bs + bsub * 16384;
    int bro = (wid & 1) * 64;             // row offset within sub-tile

    f32x4 acc[8][4] = {};

    for (int kt = 0; kt < DDIM / BK; ++kt) {
        __syncthreads();
#pragma unroll
        for (int j = 0; j < 8; ++j)
            gll16(bsrcw + ((size_t)kt << 14) + j * 1024, bldsw + j * 1024);
        {
            uint4 v[4];
            if (token >= 0) {
                const uint4* p = (const uint4*)(arow + kt * BK);
#pragma unroll
                for (int i = 0; i < 4; ++i) v[i] = p[i];
            } else {
#pragma unroll
                for (int i = 0; i < 4; ++i) v[i] = make_uint4(0u, 0u, 0u, 0u);
            }
#pragma unroll
            for (int i = 0; i < 4; ++i)
                *(uint4*)(As + swz(ar, ach * 64 + i * 16)) = v[i];
        }
        __syncthreads();

#pragma unroll
        for (int kk = 0; kk < 2; ++kk) {
            bf16x8 bfr[4];
#pragma unroll
            for (int n = 0; n < 4; ++n)
                bfr[n] = *(const bf16x8*)(bfrag + swz(bro + n * 16 + lr, kk * 64 + lhi * 16));
#pragma unroll
            for (int m = 0; m < 8; ++m) {
                bf16x8 af = *(const bf16x8*)(As + swz(m * 16 + lr, kk * 64 + lhi * 16));
#pragma unroll
                for (int n = 0; n < 4; ++n)
                    acc[m][n] = __builtin_amdgcn_mfma_f32_16x16x32_bf16(af, bfr[n], acc[m][n], 0, 0, 0);
            }
        }
    }

    float bias[4];
#pragma unroll
    for (int n = 0; n < 4; ++n) bias[n] = b1e[n0 + wid * 64 + n * 16 + lr];

#pragma unroll
    for (int m = 0; m < 8; ++m) {
        int rbase = m * 16 + lhi * 4;
#pragma unroll
        for (int j = 0; j < 4; ++j) {
            int rl = rbase + j;
            if (rl < rows_here) {
                __bf16* hr = H + (size_t)(start + row0 + rl - hbase) * FFDIM + n0 + wid * 64;
#pragma unroll
                for (int n = 0; n < 4; ++n) {
                    float v = acc[m][n][j] + bias[n];
                    hr[n * 16 + lr] = (__bf16)gelu_fast(v);
                }
            }
        }
    }
}

// ---------------- FAST GEMM2: same geometry; 1-D XCD-chunked (NTN=4) ----------------
__global__ __launch_bounds__(256)
void gemm2_fast(const __bf16* __restrict__ H, const __bf16* __restrict__ W2T,
                const float* __restrict__ b2,
                const int* __restrict__ perm, const float* __restrict__ gate_slot,
                const int* __restrict__ counts, const int* __restrict__ offsets,
                const int* __restrict__ tiletab,
                float* __restrict__ out, __bf16* __restrict__ Y, int use_y,
                int e_arg, int c_arg, int CH)
{
    __shared__ __align__(16) char smem[48 * 1024];
    char* As = smem;
    char* Bs = smem + 16384;

    const int NTN = DDIM / BN2; // 4
    int tile_idx, ntb;
    if (e_arg >= 0) { ntb = blockIdx.x; tile_idx = blockIdx.y; }
    else {
        int L = xcd_logical(blockIdx.x, gridDim.x);
        ntb = L % NTN;
        tile_idx = L / NTN;
    }

    int e, start, cnt, hbase, row0, rows_here;
    if (!tile_header(counts, offsets, tiletab, e_arg, c_arg, CH, tile_idx,
                     e, start, cnt, hbase, row0, rows_here))
        return;

    const float* b2e = b2 + (size_t)e * DDIM;
    int n0 = ntb * BN2;
    const int ktiles = FFDIM >> 6;        // 64
    const char* bpanel = (const char*)W2T +
        ((((size_t)e * (DDIM >> 7) + 2 * ntb) * ktiles) << 14);
    const size_t substride = (size_t)ktiles << 14;

    int tid = threadIdx.x;
    int lane = tid & 63;
    int wid = tid >> 6;
    int lr = lane & 15, lhi = lane >> 4;

    int ar = tid >> 1, ach = tid & 1;
    bool aval = (ar < rows_here);
    const __bf16* hrow = H + (size_t)(aval ? (start + row0 + ar - hbase) : 0) * FFDIM + ach * 32;

    int bsub = wid >> 1;
    const char* bsrcw = bpanel + bsub * substride + (wid & 1) * 8192 + lane * 16;
    char* bldsw = Bs + wid * 8192;
    const char* bfrag = Bs + bsub * 16384;
    int bro = (wid & 1) * 64;

    f32x4 acc[8][4] = {};

    for (int kt = 0; kt < FFDIM / BK; ++kt) {
        __syncthreads();
#pragma unroll
        for (int j = 0; j < 8; ++j)
            gll16(bsrcw + ((size_t)kt << 14) + j * 1024, bldsw + j * 1024);
        {
            uint4 v[4];
            if (aval) {
                const uint4* p = (const uint4*)(hrow + kt * BK);
#pragma unroll
                for (int i = 0; i < 4; ++i) v[i] = p[i];
            } else {
#pragma unroll
                for (int i = 0; i < 4; ++i) v[i] = make_uint4(0u, 0u, 0u, 0u);
            }
#pragma unroll
            for (int i = 0; i < 4; ++i)
                *(uint4*)(As + swz(ar, ach * 64 + i * 16)) = v[i];
        }
        __syncthreads();

#pragma unroll
        for (int kk = 0; kk < 2; ++kk) {
            bf16x8 bfr[4];
#pragma unroll
            for (int n = 0; n < 4; ++n)
                bfr[n] = *(const bf16x8*)(bfrag + swz(bro + n * 16 + lr, kk * 64 + lhi * 16));
#pragma unroll
            for (int m = 0; m < 8; ++m) {
                bf16x8 af = *(const bf16x8*)(As + swz(m * 16 + lr, kk * 64 + lhi * 16));
#pragma unroll
                for (int n = 0; n < 4; ++n)
                    acc[m][n] = __builtin_amdgcn_mfma_f32_16x16x32_bf16(af, bfr[n], acc[m][n], 0, 0, 0);
            }
        }
    }

    float bias[4];
#pragma unroll
    for (int n = 0; n < 4; ++n) bias[n] = b2e[n0 + wid * 64 + n * 16 + lr];

#pragma unroll
    for (int m = 0; m < 8; ++m) {
        int rbase = m * 16 + lhi * 4;
#pragma unroll
        for (int j = 0; j < 4; ++j) {
            int rl = rbase + j;
            if (rl < rows_here) {
                int slot = start + row0 + rl;
                float g = gate_slot[slot];
                if (use_y) {
                    __bf16* yrow = Y + (size_t)slot * DDIM + n0 + wid * 64;
#pragma unroll
                    for (int n = 0; n < 4; ++n)
                        yrow[n * 16 + lr] = (__bf16)((acc[m][n][j] + bias[n]) * g);
                } else {
                    int token = perm[slot];
                    float* orow = out + (size_t)token * DDIM + n0 + wid * 64;
#pragma unroll
                    for (int n = 0; n < 4; ++n)
                        atomicAdd(orow + n * 16 + lr, (acc[m][n][j] + bias[n]) * g);
                }
            }
        }
    }
}

// ---------------- combine: out[t] = Y[slot_a] + Y[slot_b]  (Y bf16) ----------------
__global__ __launch_bounds__(256)
void combine_kernel(const __bf16* __restrict__ Y, const int* __restrict__ tslot,
                    float* __restrict__ out)
{
    int t = blockIdx.x;
    int c = threadIdx.x * 4;
    int sa = tslot[2 * t], sb = tslot[2 * t + 1];
    bf16x4 a = *(const bf16x4*)(Y + (size_t)sa * DDIM + c);
    bf16x4 b = *(const bf16x4*)(Y + (size_t)sb * DDIM + c);
    float4 r;
    r.x = (float)a[0] + (float)b[0];
    r.y = (float)a[1] + (float)b[1];
    r.z = (float)a[2] + (float)b[2];
    r.w = (float)a[3] + (float)b[3];
    *(float4*)(out + (size_t)t * DDIM + c) = r;
}

// ---------------- LEGACY kernels (fp32 weights, tiny-ws fallback) ----------------
__global__ __launch_bounds__(256)
void gemm1_legacy(const float* __restrict__ x, const float* __restrict__ W1,
                  const float* __restrict__ b1,
                  const int* __restrict__ perm, const int* __restrict__ counts,
                  const int* __restrict__ offsets, const int* __restrict__ tiletab,
                  __bf16* __restrict__ H, int e_arg, int c_arg, int CH)
{
    __shared__ __align__(16) char smem[(BM + 128) * 128];
    char* As = smem;
    char* Bs = smem + BM * 128;

    int e, start, cnt, hbase, row0, rows_here;
    if (!tile_header(counts, offsets, tiletab, e_arg, c_arg, CH, blockIdx.y,
                     e, start, cnt, hbase, row0, rows_here))
        return;

    const float* W1e = W1 + (size_t)e * DDIM * FFDIM;
    const float* b1e = b1 + (size_t)e * FFDIM;
    int n0 = blockIdx.x * 128;

    int tid = threadIdx.x;
    int lane = tid & 63;
    int wid = tid >> 6;
    int wm = wid >> 1, wn = wid & 1;
    int lr = lane & 15, lhi = lane >> 4;

    int ar = tid >> 1, ach = tid & 1;
    int token = -1;
    if (ar < rows_here) token = perm[start + row0 + ar];
    const float* arow = x + (size_t)(token < 0 ? 0 : token) * DDIM + ach * 32;

    int bn = tid & 127, bkh = tid >> 7;
    const float* bcol = W1e + (size_t)bkh * 32 * FFDIM + n0 + bn;

    f32x4 acc[4][4] = {};

    for (int k0 = 0; k0 < DDIM; k0 += BK) {
        __syncthreads();
        {
            BF8 pk[4];
            if (token >= 0) {
                const float4* p = (const float4*)(arow + k0);
#pragma unroll
                for (int i = 0; i < 4; ++i) {
                    float4 v0 = p[2 * i], v1 = p[2 * i + 1];
                    pk[i].b[0] = (__bf16)v0.x; pk[i].b[1] = (__bf16)v0.y;
                    pk[i].b[2] = (__bf16)v0.z; pk[i].b[3] = (__bf16)v0.w;
                    pk[i].b[4] = (__bf16)v1.x; pk[i].b[5] = (__bf16)v1.y;
                    pk[i].b[6] = (__bf16)v1.z; pk[i].b[7] = (__bf16)v1.w;
                }
            } else {
#pragma unroll
                for (int i = 0; i < 4; ++i) pk[i].u = make_uint4(0u, 0u, 0u, 0u);
            }
#pragma unroll
            for (int i = 0; i < 4; ++i)
                *(uint4*)(As + swz(ar, ach * 64 + i * 16)) = pk[i].u;
        }
        {
            float f[32];
            const float* p = bcol + (size_t)k0 * FFDIM;
#pragma unroll
            for (int j = 0; j < 32; ++j) f[j] = p[(size_t)j * FFDIM];
#pragma unroll
            for (int i = 0; i < 4; ++i) {
                BF8 pk;
#pragma unroll
                for (int q = 0; q < 8; ++q) pk.b[q] = (__bf16)f[i * 8 + q];
                *(uint4*)(Bs + swz(bn, bkh * 64 + i * 16)) = pk.u;
            }
        }
        __syncthreads();

#pragma unroll
        for (int kk = 0; kk < 2; ++kk) {
            bf16x8 af[4], bfr[4];
#pragma unroll
            for (int m = 0; m < 4; ++m)
                af[m] = *(const bf16x8*)(As + swz(wm * 64 + m * 16 + lr, kk * 64 + lhi * 16));
#pragma unroll
            for (int n = 0; n < 4; ++n)
                bfr[n] = *(const bf16x8*)(Bs + swz(wn * 64 + n * 16 + lr, kk * 64 + lhi * 16));
#pragma unroll
            for (int m = 0; m < 4; ++m)
#pragma unroll
                for (int n = 0; n < 4; ++n)
                    acc[m][n] = __builtin_amdgcn_mfma_f32_16x16x32_bf16(af[m], bfr[n], acc[m][n], 0, 0, 0);
        }
    }

    float bias[4];
#pragma unroll
    for (int n = 0; n < 4; ++n) bias[n] = b1e[n0 + wn * 64 + n * 16 + lr];

#pragma unroll
    for (int m = 0; m < 4; ++m) {
        int rbase = wm * 64 + m * 16 + lhi * 4;
#pragma unroll
        for (int j = 0; j < 4; ++j) {
            int rl = rbase + j;
            if (rl < rows_here) {
                __bf16* hr = H + (size_t)(start + row0 + rl - hbase) * FFDIM + n0 + wn * 64;
#pragma unroll
                for (int n = 0; n < 4; ++n) {
                    float v = acc[m][n][j] + bias[n];
                    hr[n * 16 + lr] = (__bf16)gelu_fast(v);
                }
            }
        }
    }
}

__global__ __launch_bounds__(256)
void gemm2_legacy(const __bf16* __restrict__ H, const float* __restrict__ W2,
                  const float* __restrict__ b2,
                  const int* __restrict__ perm, const float* __restrict__ gate_slot,
                  const int* __restrict__ counts, const int* __restrict__ offsets,
                  const int* __restrict__ tiletab,
                  float* __restrict__ out, int e_arg, int c_arg, int CH)
{
    __shared__ __align__(16) char smem[(BM + 128) * 128];
    char* As = smem;
    char* Bs = smem + BM * 128;

    int e, start, cnt, hbase, row0, rows_here;
    if (!tile_header(counts, offsets, tiletab, e_arg, c_arg, CH, blockIdx.y,
                     e, start, cnt, hbase, row0, rows_here))
        return;

    const float* W2e = W2 + (size_t)e * FFDIM * DDIM;
    const float* b2e = b2 + (size_t)e * DDIM;
    int n0 = blockIdx.x * 128;

    int tid = threadIdx.x;
    int lane = tid & 63;
    int wid = tid >> 6;
    int wm = wid >> 1, wn = wid & 1;
    int lr = lane & 15, lhi = lane >> 4;

    int ar = tid >> 1, ach = tid & 1;
    bool aval = (ar < rows_here);
    const __bf16* hrow = H + (size_t)(aval ? (start + row0 + ar - hbase) : 0) * FFDIM + ach * 32;

    int bn = tid & 127, bkh = tid >> 7;
    const float* bcol = W2e + (size_t)bkh * 32 * DDIM + n0 + bn;

    f32x4 acc[4][4] = {};

    for (int k0 = 0; k0 < FFDIM; k0 += BK) {
        __syncthreads();
        {
            uint4 v[4];
            if (aval) {
                const uint4* p = (const uint4*)(hrow + k0);
#pragma unroll
                for (int i = 0; i < 4; ++i) v[i] = p[i];
            } else {
#pragma unroll
                for (int i = 0; i < 4; ++i) v[i] = make_uint4(0u, 0u, 0u, 0u);
            }
#pragma unroll
            for (int i = 0; i < 4; ++i)
                *(uint4*)(As + swz(ar, ach * 64 + i * 16)) = v[i];
        }
        {
            float f[32];
            const float* p = bcol + (size_t)k0 * DDIM;
#pragma unroll
            for (int j = 0; j < 32; ++j) f[j] = p[(size_t)j * DDIM];
#pragma unroll
            for (int i = 0; i < 4; ++i) {
                BF8 pk;
#pragma unroll
                for (int q = 0; q < 8; ++q) pk.b[q] = (__bf16)f[i * 8 + q];
                *(uint4*)(Bs + swz(bn, bkh * 64 + i * 16)) = pk.u;
            }
        }
        __syncthreads();

#pragma unroll
        for (int kk = 0; kk < 2; ++kk) {
            bf16x8 af[4], bfr[4];
#pragma unroll
            for (int m = 0; m < 4; ++m)
                af[m] = *(const bf16x8*)(As + swz(wm * 64 + m * 16 + lr, kk * 64 + lhi * 16));
#pragma unroll
            for (int n = 0; n < 4; ++n)
                bfr[n] = *(const bf16x8*)(Bs + swz(wn * 64 + n * 16 + lr, kk * 64 + lhi * 16));
#pragma unroll
            for (int m = 0; m < 4; ++m)
#pragma unroll
                for (int n = 0; n < 4; ++n)
                    acc[m][n] = __builtin_amdgcn_mfma_f32_16x16x32_bf16(af[m], bfr[n], acc[m][n], 0, 0, 0);
        }
    }

    float bias[4];
#pragma unroll
    for (int n = 0; n < 4; ++n) bias[n] = b2e[n0 + wn * 64 + n * 16 + lr];

#pragma unroll
    for (int m = 0; m < 4; ++m) {
        int rbase = wm * 64 + m * 16 + lhi * 4;
#pragma unroll
        for (int j = 0; j < 4; ++j) {
            int rl = rbase + j;
            if (rl < rows_here) {
                int slot = start + row0 + rl;
                int token = perm[slot];
                float g = gate_slot[slot];
                float* orow = out + (size_t)token * DDIM + n0 + wn * 64;
#pragma unroll
                for (int n = 0; n < 4; ++n) {
                    float v = (acc[m][n][j] + bias[n]) * g;
                    atomicAdd(orow + n * 16 + lr, v);
                }
            }
        }
    }
}

extern "C" void kernel_launch(void* const* d_in, const int* in_sizes, int n_in,
                              void* d_out, int out_size, void* d_ws, size_t ws_size,
                              hipStream_t stream)
{
    const float* x  = (const float*)d_in[0];
    const float* Wr = (const float*)d_in[1];
    const float* W1 = (const float*)d_in[2];
    const float* b1 = (const float*)d_in[3];
    const float* W2 = (const float*)d_in[4];
    const float* b2 = (const float*)d_in[5];
    float* out = (float*)d_out;

    char* ws = (char*)d_ws;
    int* counts   = (int*)ws;
    int* offsets  = counts + 8;
    int* cursors  = offsets + 8;
    int* tiletab  = cursors + 8;               // 2*MAXT
    int* idx2     = tiletab + 2 * MAXT;        // 2*NTOK
    float* gates2 = (float*)(idx2 + 2 * NTOK); // 2*NTOK
    int* perm     = (int*)(gates2 + 2 * NTOK); // NSLOT
    float* gate_slot = (float*)(perm + NSLOT); // NSLOT
    int* tslot    = (int*)(gate_slot + NSLOT); // 2*NTOK
    char* hraw = (char*)(tslot + 2 * NTOK);
    size_t small_end = (((size_t)(hraw - ws)) + 255) & ~(size_t)255;

    // fast-path layout
    __bf16* xb  = (__bf16*)(ws + small_end);                 // 16 MiB
    __bf16* W1T = xb + (size_t)NTOK * DDIM;                  // 64 MiB
    __bf16* W2T = W1T + (size_t)NEXP * DDIM * FFDIM;         // 64 MiB
    __bf16* Hf  = W2T + (size_t)NEXP * FFDIM * DDIM;
    __bf16* Y   = W1T;  // aliases W1T: dead after gemm1; bf16 Y = 32 MiB
    size_t fast_off = small_end + ((size_t)NTOK * DDIM + 2 * (size_t)NEXP * DDIM * FFDIM) * 2;
    size_t availHf = ws_size > fast_off ? ws_size - fast_off : 0;
    size_t need_H = (size_t)NSLOT * FFDIM * 2;
    bool have_w = availHf >= (size_t)BM * FFDIM * 2 * 8;

    hipMemsetAsync(counts, 0, 8 * sizeof(int), stream);

    router_kernel<<<NTOK / 4, 256, 0, stream>>>(x, Wr, xb, have_w ? 1 : 0,
                                                idx2, gates2, counts);
    if (have_w) {
        convert_w_kernel<<<dim3(512, 2 * NEXP), 256, 0, stream>>>(W1, W2, W1T, W2T);
    }
    offsets_kernel<<<1, 256, 0, stream>>>(counts, offsets, cursors, tiletab);
    fill_kernel<<<NTOK / 256, 256, 0, stream>>>(idx2, gates2, offsets, cursors, perm, gate_slot, tslot);

    if (have_w && availHf >= need_H) {
        dim3 g1(FFDIM / BN2, MAXT, 1);   // 16 x 136
        gemm1_fast<<<g1, 256, 0, stream>>>(xb, W1T, b1, perm, counts, offsets, tiletab, Hf, -1, 0, 0);
        gemm2_fast<<<(DDIM / BN2) * MAXT, 256, 0, stream>>>(Hf, W2T, b2, perm, gate_slot, counts,
                                                            offsets, tiletab, out, Y, 1, -1, 0, 0);
        combine_kernel<<<NTOK, 256, 0, stream>>>(Y, tslot, out);
    } else if (have_w) {
        hipMemsetAsync(d_out, 0, (size_t)out_size * sizeof(float), stream);
        long long chl = (long long)((availHf / ((size_t)FFDIM * 2)) / BM) * BM;
        int CH = (int)(chl > 4096 ? 4096 : chl);
        int nchunk = (NSLOT + CH - 1) / CH;
        for (int e = 0; e < NEXP; ++e) {
            for (int c = 0; c < nchunk; ++c) {
                dim3 g1(FFDIM / BN2, CH / BM, 1);
                gemm1_fast<<<g1, 256, 0, stream>>>(xb, W1T, b1, perm, counts, offsets, tiletab, Hf, e, c, CH);
                dim3 g2(DDIM / BN2, CH / BM, 1);
                gemm2_fast<<<g2, 256, 0, stream>>>(Hf, W2T, b2, perm, gate_slot, counts, offsets, tiletab,
                                                   out, (__bf16*)nullptr, 0, e, c, CH);
            }
        }
    } else {
        hipMemsetAsync(d_out, 0, (size_t)out_size * sizeof(float), stream);
        __bf16* H = (__bf16*)(ws + small_end);
        size_t avail = ws_size > small_end ? ws_size - small_end : 0;
        if (avail >= need_H) {
            dim3 g1(FFDIM / 128, MAXT, 1);
            gemm1_legacy<<<g1, 256, 0, stream>>>(x, W1, b1, perm, counts, offsets, tiletab, H, -1, 0, 0);
            dim3 g2(DDIM / 128, MAXT, 1);
            gemm2_legacy<<<g2, 256, 0, stream>>>(H, W2, b2, perm, gate_slot, counts, offsets, tiletab, out, -1, 0, 0);
        } else {
            long long chl = (long long)((avail / ((size_t)FFDIM * 2)) / BM) * BM;
            int CH = (int)(chl > 2048 ? 2048 : chl);
            if (CH >= BM) {
                int nchunk = (NSLOT + CH - 1) / CH;
                for (int e = 0; e < NEXP; ++e) {
                    for (int c = 0; c < nchunk; ++c) {
                        dim3 g1(FFDIM / 128, CH / BM, 1);
                        gemm1_legacy<<<g1, 256, 0, stream>>>(x, W1, b1, perm, counts, offsets, tiletab, H, e, c, CH);
                        dim3 g2(DDIM / 128, CH / BM, 1);
                        gemm2_legacy<<<g2, 256, 0, stream>>>(H, W2, b2, perm, gate_slot, counts, offsets, tiletab, out, e, c, CH);
                    }
                }
            }
        }
    }
}

// Round 18
// 764.894 us; speedup vs baseline: 1.4605x; 1.4605x over previous
//
#include <hip/hip_runtime.h>
#include <hip/hip_bf16.h>
#include <math.h>

#define NEXP 8
#define DDIM 1024
#define FFDIM 4096
#define NTOK 8192
#define NSLOT (NTOK * 2)
#define BM 128
#define BN 128
#define BK 64
#define MAXT ((NSLOT / BM) + NEXP) /* 136 worst-case row tiles */

typedef __attribute__((ext_vector_type(8))) __bf16 bf16x8;
typedef __attribute__((ext_vector_type(4))) __bf16 bf16x4;
typedef __attribute__((ext_vector_type(4))) float f32x4;

union BF8 { __bf16 b[8]; uint4 u; bf16x8 v; };

// async global->LDS, 16B per lane; LDS dest = wave-uniform base + lane*16
typedef const __attribute__((address_space(1))) void* gptr1_t;
typedef __attribute__((address_space(3))) void* lptr3_t;
__device__ __forceinline__ void gll16(const void* g, void* l) {
    __builtin_amdgcn_global_load_lds((gptr1_t)g, (lptr3_t)l, 16, 0, 0);
}

// Fast GELU (tanh form) — ~1e-4 max abs dev from exact erf form.
__device__ __forceinline__ float gelu_fast(float v) {
    float vv = v * v;
    float ex = __expf(v * fmaf(0.0713548162726f, vv, 1.59576912161f));
    float s = __builtin_amdgcn_rcpf(ex + 1.0f);
    return v * (1.0f - s);
}

// Swizzled byte offset inside a [rows][64 bf16] tile (128B rows).
__device__ __forceinline__ int swz(int row, int colb) {
    return row * 128 + (colb ^ ((row & 7) << 4));
}

// XCD chunked swizzle (gemm2 only — measured win there, loss on gemm1).
__device__ __forceinline__ int xcd_logical(int bid, int nwg) {
    if (nwg & 7) return bid;
    return (bid & 7) * (nwg >> 3) + (bid >> 3);
}

// ---------------- router + fused x->bf16 conversion ----------------
__global__ __launch_bounds__(256)
void router_kernel(const float* __restrict__ x, const float* __restrict__ Wr,
                   __bf16* __restrict__ xb, int write_xb,
                   int* __restrict__ idx2, float* __restrict__ gates2,
                   int* __restrict__ counts)
{
    int tid = threadIdx.x;
    int t = blockIdx.x * 4 + (tid >> 6);
    int lane = tid & 63;
    const float* xr = x + (size_t)t * DDIM;

    float acc[NEXP];
#pragma unroll
    for (int e = 0; e < NEXP; ++e) acc[e] = 0.f;

#pragma unroll
    for (int i = 0; i < 2; ++i) {
        int d0 = i * 512 + lane * 8;
        float4 a = *(const float4*)(xr + d0);
        float4 b = *(const float4*)(xr + d0 + 4);
        float vals[8] = {a.x, a.y, a.z, a.w, b.x, b.y, b.z, b.w};
#pragma unroll
        for (int q = 0; q < 8; ++q) {
            const float* wrow = Wr + (size_t)(d0 + q) * NEXP;
#pragma unroll
            for (int e = 0; e < NEXP; ++e) acc[e] += vals[q] * wrow[e];
        }
        if (write_xb) {
            BF8 pk;
#pragma unroll
            for (int q = 0; q < 8; ++q) pk.b[q] = (__bf16)vals[q];
            *(uint4*)(xb + (size_t)t * DDIM + d0) = pk.u;
        }
    }
#pragma unroll
    for (int e = 0; e < NEXP; ++e) {
        float v = acc[e];
        for (int off = 32; off > 0; off >>= 1) v += __shfl_xor(v, off, 64);
        acc[e] = v;
    }
    if (lane == 0) {
        float mx = acc[0];
#pragma unroll
        for (int e = 1; e < NEXP; ++e) mx = fmaxf(mx, acc[e]);
        float p[NEXP]; float s = 0.f;
#pragma unroll
        for (int e = 0; e < NEXP; ++e) { p[e] = expf(acc[e] - mx); s += p[e]; }
        float inv = 1.f / s;
#pragma unroll
        for (int e = 0; e < NEXP; ++e) p[e] *= inv;
        int i1 = 0; float p1 = p[0];
#pragma unroll
        for (int e = 1; e < NEXP; ++e) if (p[e] > p1) { p1 = p[e]; i1 = e; }
        int i2 = -1; float p2 = -1.f;
#pragma unroll
        for (int e = 0; e < NEXP; ++e) {
            if (e == i1) continue;
            if (p[e] > p2) { p2 = p[e]; i2 = e; }
        }
        float u = expf(p2 - p1);
        float den = 1.f + u;
        idx2[2 * t] = i1; idx2[2 * t + 1] = i2;
        gates2[2 * t] = 1.f / den; gates2[2 * t + 1] = u / den;
        atomicAdd(&counts[i1], 1);
        atomicAdd(&counts[i2], 1);
    }
}

// ---------------- offsets + tile table (parallel) ----------------
__global__ __launch_bounds__(256)
void offsets_kernel(const int* __restrict__ counts, int* __restrict__ offsets,
                    int* __restrict__ cursors, int* __restrict__ tiletab)
{
    __shared__ int soff[NEXP], stile[NEXP + 1];
    int tid = threadIdx.x;
    if (tid == 0) {
        int off = 0, tt = 0;
        for (int e = 0; e < NEXP; ++e) {
            soff[e] = off; stile[e] = tt;
            int c = counts[e];
            off += c; tt += (c + BM - 1) / BM;
        }
        stile[NEXP] = tt;
    }
    __syncthreads();
    if (tid < NEXP) { offsets[tid] = soff[tid]; cursors[tid] = 0; }
    int total = stile[NEXP];
    for (int i = tid; i < MAXT; i += 256) {
        if (i < total) {
            int e = 0;
            while (stile[e + 1] <= i) ++e;
            tiletab[2 * i] = e; tiletab[2 * i + 1] = i - stile[e];
        } else {
            tiletab[2 * i] = -1; tiletab[2 * i + 1] = 0;
        }
    }
}

// ---------------- fill permutation (+ inverse token->slots) ----------------
__global__ __launch_bounds__(256)
void fill_kernel(const int* __restrict__ idx2, const float* __restrict__ gates2,
                 const int* __restrict__ offsets, int* __restrict__ cursors,
                 int* __restrict__ perm, float* __restrict__ gate_slot,
                 int* __restrict__ tslot)
{
    int t = blockIdx.x * 256 + threadIdx.x;
    if (t >= NTOK) return;
#pragma unroll
    for (int s = 0; s < 2; ++s) {
        int e = idx2[2 * t + s];
        int pos = atomicAdd(&cursors[e], 1);
        int slot = offsets[e] + pos;
        perm[slot] = t;
        gate_slot[slot] = gates2[2 * t + s];
        tslot[2 * t + s] = slot;
    }
}

// Fused W1+W2 conversion with COALESCED writes (r16-proven).
__global__ __launch_bounds__(256)
void convert_w_kernel(const float* __restrict__ W1, const float* __restrict__ W2,
                      __bf16* __restrict__ W1T, __bf16* __restrict__ W2T)
{
    __shared__ float tile[64][133];
    int y = blockIdx.y;
    const float* W; __bf16* WT; int K, N, e;
    if (y < NEXP) { W = W1; WT = W1T; K = DDIM; N = FFDIM; e = y; }
    else          { W = W2; WT = W2T; K = FFDIM; N = DDIM; e = y - NEXP; }
    int ktiles = K >> 6;
    int nt = blockIdx.x / ktiles;
    int kt = blockIdx.x % ktiles;
    const float* We = W + (size_t)e * K * N + (size_t)(kt * 64) * N + nt * 128;
    int tid = threadIdx.x;

    int kr = tid >> 5;
    int n4 = (tid & 31) * 4;
#pragma unroll
    for (int i = 0; i < 8; ++i) {
        int k = kr + i * 8;
        float4 v = *(const float4*)(We + (size_t)k * N + n4);
        tile[k][n4] = v.x; tile[k][n4 + 1] = v.y;
        tile[k][n4 + 2] = v.z; tile[k][n4 + 3] = v.w;
    }
    __syncthreads();

    char* dstb = (char*)WT + ((((size_t)e * (N >> 7) + nt) * ktiles + kt) << 14);
#pragma unroll
    for (int it = 0; it < 4; ++it) {
        int off = it * 4096 + tid * 16;
        int r = off >> 7;
        int s = (off >> 4) & 7;
        int gi = s ^ (r & 7);
        BF8 pk;
#pragma unroll
        for (int q = 0; q < 8; ++q) pk.b[q] = (__bf16)tile[gi * 8 + q][r];
        *(uint4*)(dstb + off) = pk.u;
    }
}

// ---------------- shared tile-header logic ----------------
__device__ __forceinline__ bool tile_header(const int* counts, const int* offsets,
                                            const int* tiletab, int e_arg, int c_arg, int CH,
                                            int tile_idx,
                                            int& e, int& start, int& cnt, int& hbase, int& row0,
                                            int& rows_here)
{
    int rowtile;
    if (e_arg >= 0) {
        e = e_arg;
        int cbase = c_arg * CH;
        cnt = counts[e] - cbase;
        if (cnt <= 0) return false;
        if (cnt > CH) cnt = CH;
        start = offsets[e] + cbase;
        rowtile = tile_idx;
        hbase = start;
    } else {
        e = tiletab[2 * tile_idx];
        if (e < 0) return false;
        rowtile = tiletab[2 * tile_idx + 1];
        start = offsets[e];
        cnt = counts[e];
        hbase = 0;
    }
    row0 = rowtile * BM;
    if (row0 >= cnt) return false;
    rows_here = cnt - row0;
    if (rows_here > BM) rows_here = BM;
    return true;
}

// ---------------- FAST GEMM1 (r11-proven): A via LDS reg-stage, B via gll; 2-D grid ----
__global__ __launch_bounds__(256)
void gemm1_fast(const __bf16* __restrict__ xb, const __bf16* __restrict__ W1T,
                const float* __restrict__ b1,
                const int* __restrict__ perm, const int* __restrict__ counts,
                const int* __restrict__ offsets, const int* __restrict__ tiletab,
                __bf16* __restrict__ H, int e_arg, int c_arg, int CH)
{
    __shared__ __align__(16) char smem[(BM + BN) * 128]; // 32 KiB
    char* As = smem;
    char* Bs = smem + BM * 128;

    int e, start, cnt, hbase, row0, rows_here;
    if (!tile_header(counts, offsets, tiletab, e_arg, c_arg, CH, blockIdx.y,
                     e, start, cnt, hbase, row0, rows_here))
        return;

    const float* b1e = b1 + (size_t)e * FFDIM;
    int nt = blockIdx.x;
    int n0 = nt * BN;
    const char* bsrc = (const char*)W1T + ((((size_t)e * (FFDIM >> 7) + nt) * (DDIM >> 6)) << 14);

    int tid = threadIdx.x;
    int lane = tid & 63;
    int wid = tid >> 6;
    int wm = wid >> 1, wn = wid & 1;
    int lr = lane & 15, lhi = lane >> 4;

    int ar = tid >> 1, ach = tid & 1;
    int token = -1;
    if (ar < rows_here) token = perm[start + row0 + ar];
    const __bf16* arow = xb + (size_t)(token < 0 ? 0 : token) * DDIM + ach * 32;

    const char* bwave = bsrc + wid * 4096 + lane * 16;
    char* bldsb = Bs + wid * 4096;

    f32x4 acc[4][4] = {};

    for (int kt = 0; kt < DDIM / BK; ++kt) {
        __syncthreads();
#pragma unroll
        for (int j = 0; j < 4; ++j)
            gll16(bwave + ((size_t)kt << 14) + j * 1024, bldsb + j * 1024);
        {
            uint4 v[4];
            if (token >= 0) {
                const uint4* p = (const uint4*)(arow + kt * BK);
#pragma unroll
                for (int i = 0; i < 4; ++i) v[i] = p[i];
            } else {
#pragma unroll
                for (int i = 0; i < 4; ++i) v[i] = make_uint4(0u, 0u, 0u, 0u);
            }
#pragma unroll
            for (int i = 0; i < 4; ++i)
                *(uint4*)(As + swz(ar, ach * 64 + i * 16)) = v[i];
        }
        __syncthreads();

#pragma unroll
        for (int kk = 0; kk < 2; ++kk) {
            bf16x8 af[4], bfr[4];
#pragma unroll
            for (int m = 0; m < 4; ++m)
                af[m] = *(const bf16x8*)(As + swz(wm * 64 + m * 16 + lr, kk * 64 + lhi * 16));
#pragma unroll
            for (int n = 0; n < 4; ++n)
                bfr[n] = *(const bf16x8*)(Bs + swz(wn * 64 + n * 16 + lr, kk * 64 + lhi * 16));
#pragma unroll
            for (int m = 0; m < 4; ++m)
#pragma unroll
                for (int n = 0; n < 4; ++n)
                    acc[m][n] = __builtin_amdgcn_mfma_f32_16x16x32_bf16(af[m], bfr[n], acc[m][n], 0, 0, 0);
        }
    }

    float bias[4];
#pragma unroll
    for (int n = 0; n < 4; ++n) bias[n] = b1e[n0 + wn * 64 + n * 16 + lr];

#pragma unroll
    for (int m = 0; m < 4; ++m) {
        int rbase = wm * 64 + m * 16 + lhi * 4;
#pragma unroll
        for (int j = 0; j < 4; ++j) {
            int rl = rbase + j;
            if (rl < rows_here) {
                __bf16* hr = H + (size_t)(start + row0 + rl - hbase) * FFDIM + n0 + wn * 64;
#pragma unroll
                for (int n = 0; n < 4; ++n) {
                    float v = acc[m][n][j] + bias[n];
                    hr[n * 16 + lr] = (__bf16)gelu_fast(v);
                }
            }
        }
    }
}

// ---------------- FAST GEMM2 (r11-proven): A reg-stage, B gll; 1-D XCD-chunked ----
__global__ __launch_bounds__(256)
void gemm2_fast(const __bf16* __restrict__ H, const __bf16* __restrict__ W2T,
                const float* __restrict__ b2,
                const int* __restrict__ perm, const float* __restrict__ gate_slot,
                const int* __restrict__ counts, const int* __restrict__ offsets,
                const int* __restrict__ tiletab,
                float* __restrict__ out, __bf16* __restrict__ Y, int use_y,
                int e_arg, int c_arg, int CH)
{
    __shared__ __align__(16) char smem[(BM + BN) * 128];
    char* As = smem;
    char* Bs = smem + BM * 128;

    const int NTN = DDIM / BN; // 8
    int tile_idx, nt;
    if (e_arg >= 0) { nt = blockIdx.x; tile_idx = blockIdx.y; }
    else {
        int L = xcd_logical(blockIdx.x, gridDim.x);
        nt = L % NTN;
        tile_idx = L / NTN;
    }

    int e, start, cnt, hbase, row0, rows_here;
    if (!tile_header(counts, offsets, tiletab, e_arg, c_arg, CH, tile_idx,
                     e, start, cnt, hbase, row0, rows_here))
        return;

    const float* b2e = b2 + (size_t)e * DDIM;
    int n0 = nt * BN;
    const char* bsrc = (const char*)W2T + ((((size_t)e * (DDIM >> 7) + nt) * (FFDIM >> 6)) << 14);

    int tid = threadIdx.x;
    int lane = tid & 63;
    int wid = tid >> 6;
    int wm = wid >> 1, wn = wid & 1;
    int lr = lane & 15, lhi = lane >> 4;

    int ar = tid >> 1, ach = tid & 1;
    bool aval = (ar < rows_here);
    const __bf16* hrow = H + (size_t)(aval ? (start + row0 + ar - hbase) : 0) * FFDIM + ach * 32;

    const char* bwave = bsrc + wid * 4096 + lane * 16;
    char* bldsb = Bs + wid * 4096;

    f32x4 acc[4][4] = {};

    for (int kt = 0; kt < FFDIM / BK; ++kt) {
        __syncthreads();
#pragma unroll
        for (int j = 0; j < 4; ++j)
            gll16(bwave + ((size_t)kt << 14) + j * 1024, bldsb + j * 1024);
        {
            uint4 v[4];
            if (aval) {
                const uint4* p = (const uint4*)(hrow + kt * BK);
#pragma unroll
                for (int i = 0; i < 4; ++i) v[i] = p[i];
            } else {
#pragma unroll
                for (int i = 0; i < 4; ++i) v[i] = make_uint4(0u, 0u, 0u, 0u);
            }
#pragma unroll
            for (int i = 0; i < 4; ++i)
                *(uint4*)(As + swz(ar, ach * 64 + i * 16)) = v[i];
        }
        __syncthreads();

#pragma unroll
        for (int kk = 0; kk < 2; ++kk) {
            bf16x8 af[4], bfr[4];
#pragma unroll
            for (int m = 0; m < 4; ++m)
                af[m] = *(const bf16x8*)(As + swz(wm * 64 + m * 16 + lr, kk * 64 + lhi * 16));
#pragma unroll
            for (int n = 0; n < 4; ++n)
                bfr[n] = *(const bf16x8*)(Bs + swz(wn * 64 + n * 16 + lr, kk * 64 + lhi * 16));
#pragma unroll
            for (int m = 0; m < 4; ++m)
#pragma unroll
                for (int n = 0; n < 4; ++n)
                    acc[m][n] = __builtin_amdgcn_mfma_f32_16x16x32_bf16(af[m], bfr[n], acc[m][n], 0, 0, 0);
        }
    }

    float bias[4];
#pragma unroll
    for (int n = 0; n < 4; ++n) bias[n] = b2e[n0 + wn * 64 + n * 16 + lr];

#pragma unroll
    for (int m = 0; m < 4; ++m) {
        int rbase = wm * 64 + m * 16 + lhi * 4;
#pragma unroll
        for (int j = 0; j < 4; ++j) {
            int rl = rbase + j;
            if (rl < rows_here) {
                int slot = start + row0 + rl;
                float g = gate_slot[slot];
                if (use_y) {
                    __bf16* yrow = Y + (size_t)slot * DDIM + n0 + wn * 64;
#pragma unroll
                    for (int n = 0; n < 4; ++n)
                        yrow[n * 16 + lr] = (__bf16)((acc[m][n][j] + bias[n]) * g);
                } else {
                    int token = perm[slot];
                    float* orow = out + (size_t)token * DDIM + n0 + wn * 64;
#pragma unroll
                    for (int n = 0; n < 4; ++n)
                        atomicAdd(orow + n * 16 + lr, (acc[m][n][j] + bias[n]) * g);
                }
            }
        }
    }
}

// ---------------- combine: out[t] = Y[slot_a] + Y[slot_b]  (Y bf16) ----------------
__global__ __launch_bounds__(256)
void combine_kernel(const __bf16* __restrict__ Y, const int* __restrict__ tslot,
                    float* __restrict__ out)
{
    int t = blockIdx.x;
    int c = threadIdx.x * 4;
    int sa = tslot[2 * t], sb = tslot[2 * t + 1];
    bf16x4 a = *(const bf16x4*)(Y + (size_t)sa * DDIM + c);
    bf16x4 b = *(const bf16x4*)(Y + (size_t)sb * DDIM + c);
    float4 r;
    r.x = (float)a[0] + (float)b[0];
    r.y = (float)a[1] + (float)b[1];
    r.z = (float)a[2] + (float)b[2];
    r.w = (float)a[3] + (float)b[3];
    *(float4*)(out + (size_t)t * DDIM + c) = r;
}

// ---------------- LEGACY kernels (fp32 weights, tiny-ws fallback) ----------------
__global__ __launch_bounds__(256)
void gemm1_legacy(const float* __restrict__ x, const float* __restrict__ W1,
                  const float* __restrict__ b1,
                  const int* __restrict__ perm, const int* __restrict__ counts,
                  const int* __restrict__ offsets, const int* __restrict__ tiletab,
                  __bf16* __restrict__ H, int e_arg, int c_arg, int CH)
{
    __shared__ __align__(16) char smem[(BM + BN) * 128];
    char* As = smem;
    char* Bs = smem + BM * 128;

    int e, start, cnt, hbase, row0, rows_here;
    if (!tile_header(counts, offsets, tiletab, e_arg, c_arg, CH, blockIdx.y,
                     e, start, cnt, hbase, row0, rows_here))
        return;

    const float* W1e = W1 + (size_t)e * DDIM * FFDIM;
    const float* b1e = b1 + (size_t)e * FFDIM;
    int n0 = blockIdx.x * BN;

    int tid = threadIdx.x;
    int lane = tid & 63;
    int wid = tid >> 6;
    int wm = wid >> 1, wn = wid & 1;
    int lr = lane & 15, lhi = lane >> 4;

    int ar = tid >> 1, ach = tid & 1;
    int token = -1;
    if (ar < rows_here) token = perm[start + row0 + ar];
    const float* arow = x + (size_t)(token < 0 ? 0 : token) * DDIM + ach * 32;

    int bn = tid & 127, bkh = tid >> 7;
    const float* bcol = W1e + (size_t)bkh * 32 * FFDIM + n0 + bn;

    f32x4 acc[4][4] = {};

    for (int k0 = 0; k0 < DDIM; k0 += BK) {
        __syncthreads();
        {
            BF8 pk[4];
            if (token >= 0) {
                const float4* p = (const float4*)(arow + k0);
#pragma unroll
                for (int i = 0; i < 4; ++i) {
                    float4 v0 = p[2 * i], v1 = p[2 * i + 1];
                    pk[i].b[0] = (__bf16)v0.x; pk[i].b[1] = (__bf16)v0.y;
                    pk[i].b[2] = (__bf16)v0.z; pk[i].b[3] = (__bf16)v0.w;
                    pk[i].b[4] = (__bf16)v1.x; pk[i].b[5] = (__bf16)v1.y;
                    pk[i].b[6] = (__bf16)v1.z; pk[i].b[7] = (__bf16)v1.w;
                }
            } else {
#pragma unroll
                for (int i = 0; i < 4; ++i) pk[i].u = make_uint4(0u, 0u, 0u, 0u);
            }
#pragma unroll
            for (int i = 0; i < 4; ++i)
                *(uint4*)(As + swz(ar, ach * 64 + i * 16)) = pk[i].u;
        }
        {
            float f[32];
            const float* p = bcol + (size_t)k0 * FFDIM;
#pragma unroll
            for (int j = 0; j < 32; ++j) f[j] = p[(size_t)j * FFDIM];
#pragma unroll
            for (int i = 0; i < 4; ++i) {
                BF8 pk;
#pragma unroll
                for (int q = 0; q < 8; ++q) pk.b[q] = (__bf16)f[i * 8 + q];
                *(uint4*)(Bs + swz(bn, bkh * 64 + i * 16)) = pk.u;
            }
        }
        __syncthreads();

#pragma unroll
        for (int kk = 0; kk < 2; ++kk) {
            bf16x8 af[4], bfr[4];
#pragma unroll
            for (int m = 0; m < 4; ++m)
                af[m] = *(const bf16x8*)(As + swz(wm * 64 + m * 16 + lr, kk * 64 + lhi * 16));
#pragma unroll
            for (int n = 0; n < 4; ++n)
                bfr[n] = *(const bf16x8*)(Bs + swz(wn * 64 + n * 16 + lr, kk * 64 + lhi * 16));
#pragma unroll
            for (int m = 0; m < 4; ++m)
#pragma unroll
                for (int n = 0; n < 4; ++n)
                    acc[m][n] = __builtin_amdgcn_mfma_f32_16x16x32_bf16(af[m], bfr[n], acc[m][n], 0, 0, 0);
        }
    }

    float bias[4];
#pragma unroll
    for (int n = 0; n < 4; ++n) bias[n] = b1e[n0 + wn * 64 + n * 16 + lr];

#pragma unroll
    for (int m = 0; m < 4; ++m) {
        int rbase = wm * 64 + m * 16 + lhi * 4;
#pragma unroll
        for (int j = 0; j < 4; ++j) {
            int rl = rbase + j;
            if (rl < rows_here) {
                __bf16* hr = H + (size_t)(start + row0 + rl - hbase) * FFDIM + n0 + wn * 64;
#pragma unroll
                for (int n = 0; n < 4; ++n) {
                    float v = acc[m][n][j] + bias[n];
                    hr[n * 16 + lr] = (__bf16)gelu_fast(v);
                }
            }
        }
    }
}

__global__ __launch_bounds__(256)
void gemm2_legacy(const __bf16* __restrict__ H, const float* __restrict__ W2,
                  const float* __restrict__ b2,
                  const int* __restrict__ perm, const float* __restrict__ gate_slot,
                  const int* __restrict__ counts, const int* __restrict__ offsets,
                  const int* __restrict__ tiletab,
                  float* __restrict__ out, int e_arg, int c_arg, int CH)
{
    __shared__ __align__(16) char smem[(BM + BN) * 128];
    char* As = smem;
    char* Bs = smem + BM * 128;

    int e, start, cnt, hbase, row0, rows_here;
    if (!tile_header(counts, offsets, tiletab, e_arg, c_arg, CH, blockIdx.y,
                     e, start, cnt, hbase, row0, rows_here))
        return;

    const float* W2e = W2 + (size_t)e * FFDIM * DDIM;
    const float* b2e = b2 + (size_t)e * DDIM;
    int n0 = blockIdx.x * BN;

    int tid = threadIdx.x;
    int lane = tid & 63;
    int wid = tid >> 6;
    int wm = wid >> 1, wn = wid & 1;
    int lr = lane & 15, lhi = lane >> 4;

    int ar = tid >> 1, ach = tid & 1;
    bool aval = (ar < rows_here);
    const __bf16* hrow = H + (size_t)(aval ? (start + row0 + ar - hbase) : 0) * FFDIM + ach * 32;

    int bn = tid & 127, bkh = tid >> 7;
    const float* bcol = W2e + (size_t)bkh * 32 * DDIM + n0 + bn;

    f32x4 acc[4][4] = {};

    for (int k0 = 0; k0 < FFDIM; k0 += BK) {
        __syncthreads();
        {
            uint4 v[4];
            if (aval) {
                const uint4* p = (const uint4*)(hrow + k0);
#pragma unroll
                for (int i = 0; i < 4; ++i) v[i] = p[i];
            } else {
#pragma unroll
                for (int i = 0; i < 4; ++i) v[i] = make_uint4(0u, 0u, 0u, 0u);
            }
#pragma unroll
            for (int i = 0; i < 4; ++i)
                *(uint4*)(As + swz(ar, ach * 64 + i * 16)) = v[i];
        }
        {
            float f[32];
            const float* p = bcol + (size_t)k0 * DDIM;
#pragma unroll
            for (int j = 0; j < 32; ++j) f[j] = p[(size_t)j * DDIM];
#pragma unroll
            for (int i = 0; i < 4; ++i) {
                BF8 pk;
#pragma unroll
                for (int q = 0; q < 8; ++q) pk.b[q] = (__bf16)f[i * 8 + q];
                *(uint4*)(Bs + swz(bn, bkh * 64 + i * 16)) = pk.u;
            }
        }
        __syncthreads();

#pragma unroll
        for (int kk = 0; kk < 2; ++kk) {
            bf16x8 af[4], bfr[4];
#pragma unroll
            for (int m = 0; m < 4; ++m)
                af[m] = *(const bf16x8*)(As + swz(wm * 64 + m * 16 + lr, kk * 64 + lhi * 16));
#pragma unroll
            for (int n = 0; n < 4; ++n)
                bfr[n] = *(const bf16x8*)(Bs + swz(wn * 64 + n * 16 + lr, kk * 64 + lhi * 16));
#pragma unroll
            for (int m = 0; m < 4; ++m)
#pragma unroll
                for (int n = 0; n < 4; ++n)
                    acc[m][n] = __builtin_amdgcn_mfma_f32_16x16x32_bf16(af[m], bfr[n], acc[m][n], 0, 0, 0);
        }
    }

    float bias[4];
#pragma unroll
    for (int n = 0; n < 4; ++n) bias[n] = b2e[n0 + wn * 64 + n * 16 + lr];

#pragma unroll
    for (int m = 0; m < 4; ++m) {
        int rbase = wm * 64 + m * 16 + lhi * 4;
#pragma unroll
        for (int j = 0; j < 4; ++j) {
            int rl = rbase + j;
            if (rl < rows_here) {
                int slot = start + row0 + rl;
                int token = perm[slot];
                float g = gate_slot[slot];
                float* orow = out + (size_t)token * DDIM + n0 + wn * 64;
#pragma unroll
                for (int n = 0; n < 4; ++n) {
                    float v = (acc[m][n][j] + bias[n]) * g;
                    atomicAdd(orow + n * 16 + lr, v);
                }
            }
        }
    }
}

extern "C" void kernel_launch(void* const* d_in, const int* in_sizes, int n_in,
                              void* d_out, int out_size, void* d_ws, size_t ws_size,
                              hipStream_t stream)
{
    const float* x  = (const float*)d_in[0];
    const float* Wr = (const float*)d_in[1];
    const float* W1 = (const float*)d_in[2];
    const float* b1 = (const float*)d_in[3];
    const float* W2 = (const float*)d_in[4];
    const float* b2 = (const float*)d_in[5];
    float* out = (float*)d_out;

    char* ws = (char*)d_ws;
    int* counts   = (int*)ws;
    int* offsets  = counts + 8;
    int* cursors  = offsets + 8;
    int* tiletab  = cursors + 8;               // 2*MAXT
    int* idx2     = tiletab + 2 * MAXT;        // 2*NTOK
    float* gates2 = (float*)(idx2 + 2 * NTOK); // 2*NTOK
    int* perm     = (int*)(gates2 + 2 * NTOK); // NSLOT
    float* gate_slot = (float*)(perm + NSLOT); // NSLOT
    int* tslot    = (int*)(gate_slot + NSLOT); // 2*NTOK
    char* hraw = (char*)(tslot + 2 * NTOK);
    size_t small_end = (((size_t)(hraw - ws)) + 255) & ~(size_t)255;

    // fast-path layout
    __bf16* xb  = (__bf16*)(ws + small_end);                 // 16 MiB
    __bf16* W1T = xb + (size_t)NTOK * DDIM;                  // 64 MiB
    __bf16* W2T = W1T + (size_t)NEXP * DDIM * FFDIM;         // 64 MiB
    __bf16* Hf  = W2T + (size_t)NEXP * FFDIM * DDIM;
    __bf16* Y   = W1T;  // aliases W1T: dead after gemm1; bf16 Y = 32 MiB
    size_t fast_off = small_end + ((size_t)NTOK * DDIM + 2 * (size_t)NEXP * DDIM * FFDIM) * 2;
    size_t availHf = ws_size > fast_off ? ws_size - fast_off : 0;
    size_t need_H = (size_t)NSLOT * FFDIM * 2;
    bool have_w = availHf >= (size_t)BM * FFDIM * 2 * 8;

    hipMemsetAsync(counts, 0, 8 * sizeof(int), stream);

    router_kernel<<<NTOK / 4, 256, 0, stream>>>(x, Wr, xb, have_w ? 1 : 0,
                                                idx2, gates2, counts);
    if (have_w) {
        convert_w_kernel<<<dim3(512, 2 * NEXP), 256, 0, stream>>>(W1, W2, W1T, W2T);
    }
    offsets_kernel<<<1, 256, 0, stream>>>(counts, offsets, cursors, tiletab);
    fill_kernel<<<NTOK / 256, 256, 0, stream>>>(idx2, gates2, offsets, cursors, perm, gate_slot, tslot);

    if (have_w && availHf >= need_H) {
        dim3 g1(FFDIM / BN, MAXT, 1);
        gemm1_fast<<<g1, 256, 0, stream>>>(xb, W1T, b1, perm, counts, offsets, tiletab, Hf, -1, 0, 0);
        gemm2_fast<<<(DDIM / BN) * MAXT, 256, 0, stream>>>(Hf, W2T, b2, perm, gate_slot, counts,
                                                           offsets, tiletab, out, Y, 1, -1, 0, 0);
        combine_kernel<<<NTOK, 256, 0, stream>>>(Y, tslot, out);
    } else if (have_w) {
        hipMemsetAsync(d_out, 0, (size_t)out_size * sizeof(float), stream);
        long long chl = (long long)((availHf / ((size_t)FFDIM * 2)) / BM) * BM;
        int CH = (int)(chl > 4096 ? 4096 : chl);
        int nchunk = (NSLOT + CH - 1) / CH;
        for (int e = 0; e < NEXP; ++e) {
            for (int c = 0; c < nchunk; ++c) {
                dim3 g1(FFDIM / BN, CH / BM, 1);
                gemm1_fast<<<g1, 256, 0, stream>>>(xb, W1T, b1, perm, counts, offsets, tiletab, Hf, e, c, CH);
                dim3 g2(DDIM / BN, CH / BM, 1);
                gemm2_fast<<<g2, 256, 0, stream>>>(Hf, W2T, b2, perm, gate_slot, counts, offsets, tiletab,
                                                   out, (__bf16*)nullptr, 0, e, c, CH);
            }
        }
    } else {
        hipMemsetAsync(d_out, 0, (size_t)out_size * sizeof(float), stream);
        __bf16* H = (__bf16*)(ws + small_end);
        size_t avail = ws_size > small_end ? ws_size - small_end : 0;
        if (avail >= need_H) {
            dim3 g1(FFDIM / BN, MAXT, 1);
            gemm1_legacy<<<g1, 256, 0, stream>>>(x, W1, b1, perm, counts, offsets, tiletab, H, -1, 0, 0);
            dim3 g2(DDIM / BN, MAXT, 1);
            gemm2_legacy<<<g2, 256, 0, stream>>>(H, W2, b2, perm, gate_slot, counts, offsets, tiletab, out, -1, 0, 0);
        } else {
            long long chl = (long long)((avail / ((size_t)FFDIM * 2)) / BM) * BM;
            int CH = (int)(chl > 2048 ? 2048 : chl);
            if (CH >= BM) {
                int nchunk = (NSLOT + CH - 1) / CH;
                for (int e = 0; e < NEXP; ++e) {
                    for (int c = 0; c < nchunk; ++c) {
                        dim3 g1(FFDIM / BN, CH / BM, 1);
                        gemm1_legacy<<<g1, 256, 0, stream>>>(x, W1, b1, perm, counts, offsets, tiletab, H, e, c, CH);
                        dim3 g2(DDIM / BN, CH / BM, 1);
                        gemm2_legacy<<<g2, 256, 0, stream>>>(H, W2, b2, perm, gate_slot, counts, offsets, tiletab, out, e, c, CH);
                    }
                }
            }
        }
    }
}